// Round 1
// baseline (123.161 us; speedup 1.0000x reference)
//
#include <hip/hip_runtime.h>
#include <math.h>

#define N_NODES 1024
#define IN_FEAT 256
#define NH 4
#define FH 32
#define F_TOT 128   // NH*FH

#define JCH 64                    // j rows per LDS chunk
#define NCH (N_NODES / JCH)       // 16 chunks
#define GJ_STRIDE 132             // floats; 132*4B=528B, 16B-aligned, 33 odd -> spread bank quads
#define A_STRIDE 1032             // pad 1024 -> 1032 to spread banks across heads

// ---------------- K1: g = h @ W, s[i][hd] = sum_f g[i,hd,f]*w[f] ----------------
__global__ __launch_bounds__(128) void gat_gemm(
    const float* __restrict__ h, const float* __restrict__ W,
    const float* __restrict__ attw, float* __restrict__ g, float* __restrict__ s)
{
    const int i = blockIdx.x;
    const int c = threadIdx.x;  // 0..127 output column
    __shared__ float hrow[IN_FEAT];
    hrow[c] = h[i * IN_FEAT + c];
    hrow[c + 128] = h[i * IN_FEAT + c + 128];
    __syncthreads();

    float acc = 0.f;
    #pragma unroll 8
    for (int k = 0; k < IN_FEAT; ++k)
        acc = fmaf(hrow[k], W[k * F_TOT + c], acc);
    g[i * F_TOT + c] = acc;

    // s[i, hd] = sum over the 32 features of this head
    float part = acc * attw[c & 31];
    #pragma unroll
    for (int d = 1; d < 32; d <<= 1)
        part += __shfl_xor(part, d);
    if ((c & 31) == 0)
        s[i * NH + (c >> 5)] = part;
}

// ---------------- K2: scores + masked softmax + aggregation + head-mean ----------------
__global__ __launch_bounds__(256) void gat_attn(
    const float* __restrict__ g, const float* __restrict__ s,
    const int* __restrict__ adj, const float* __restrict__ attw,
    float* __restrict__ out)
{
    __shared__ float gj[JCH * GJ_STRIDE];   // 33792 B, staged g chunk (also reused as `red`)
    __shared__ float ea[NH * A_STRIDE];     // 16512 B, e then a (probabilities)
    __shared__ float gi_sm[F_TOT];          // 512 B

    const int i = blockIdx.x;
    const int t = threadIdx.x;
    const int jl = t & 63;        // j within chunk
    const int hd = t >> 6;        // head, uniform per wave

    if (t < F_TOT) gi_sm[t] = g[i * F_TOT + t];
    __syncthreads();

    float gi[FH], w04[FH];
    #pragma unroll
    for (int f = 0; f < FH; ++f) {
        gi[f] = gi_sm[hd * FH + f];
        w04[f] = 0.4f * attw[f];
    }
    const float si = s[i * NH + hd];

    // ---- phase A: scores for all j, per (i, head) ----
    for (int c = 0; c < NCH; ++c) {
        // stage rows [c*64, c*64+64) of g into LDS (coalesced float4)
        #pragma unroll
        for (int r = 0; r < 8; ++r) {
            const int idx4 = r * 256 + t;
            const int j = idx4 >> 5, f4 = idx4 & 31;
            float4 v = *reinterpret_cast<const float4*>(g + (c * JCH + j) * F_TOT + f4 * 4);
            *reinterpret_cast<float4*>(&gj[j * GJ_STRIDE + f4 * 4]) = v;
        }
        __syncthreads();

        const int jg = c * JCH + jl;
        float e = 0.6f * (si + s[jg * NH + hd]);
        #pragma unroll
        for (int f4 = 0; f4 < 8; ++f4) {
            float4 v = *reinterpret_cast<const float4*>(&gj[jl * GJ_STRIDE + hd * FH + f4 * 4]);
            e = fmaf(w04[4 * f4 + 0], fabsf(gi[4 * f4 + 0] + v.x), e);
            e = fmaf(w04[4 * f4 + 1], fabsf(gi[4 * f4 + 1] + v.y), e);
            e = fmaf(w04[4 * f4 + 2], fabsf(gi[4 * f4 + 2] + v.z), e);
            e = fmaf(w04[4 * f4 + 3], fabsf(gi[4 * f4 + 3] + v.w), e);
        }
        ea[hd * A_STRIDE + jg] = adj[i * N_NODES + jg] ? e : -INFINITY;
        __syncthreads();   // protect gj before next chunk's staging
    }

    // ---- softmax over j (each thread owns jl + c*64 slots of its head's row) ----
    float m = -INFINITY;
    #pragma unroll
    for (int c = 0; c < NCH; ++c)
        m = fmaxf(m, ea[hd * A_STRIDE + c * JCH + jl]);
    #pragma unroll
    for (int d = 1; d < 64; d <<= 1)
        m = fmaxf(m, __shfl_xor(m, d));

    float pbuf[NCH];
    float l = 0.f;
    #pragma unroll
    for (int c = 0; c < NCH; ++c) {
        const float p = __expf(ea[hd * A_STRIDE + c * JCH + jl] - m);
        pbuf[c] = p;
        l += p;
    }
    #pragma unroll
    for (int d = 1; d < 64; d <<= 1)
        l += __shfl_xor(l, d);
    const float inv = 1.0f / l;
    #pragma unroll
    for (int c = 0; c < NCH; ++c)
        ea[hd * A_STRIDE + c * JCH + jl] = pbuf[c] * inv;
    __syncthreads();

    // ---- phase B: attn_res[i,h,f] = sum_j a[j]*g[j,h,f]; then mean over heads ----
    const int f4 = t & 7, h2 = (t >> 3) & 3, grp = t >> 5;  // 8 j-groups of 128
    float4 acc = {0.f, 0.f, 0.f, 0.f};
    for (int jj = 0; jj < 128; ++jj) {
        const int j = grp * 128 + jj;
        const float a = ea[h2 * A_STRIDE + j];
        float4 gv = *reinterpret_cast<const float4*>(g + j * F_TOT + h2 * FH + f4 * 4);
        acc.x = fmaf(a, gv.x, acc.x);
        acc.y = fmaf(a, gv.y, acc.y);
        acc.z = fmaf(a, gv.z, acc.z);
        acc.w = fmaf(a, gv.w, acc.w);
    }
    float* red = gj;  // alias: gj no longer needed
    *reinterpret_cast<float4*>(&red[t * 4]) = acc;
    __syncthreads();

    if (t < FH) {
        float v = 0.f;
        #pragma unroll
        for (int grp2 = 0; grp2 < 8; ++grp2)
            #pragma unroll
            for (int hh = 0; hh < NH; ++hh)
                v += red[grp2 * 128 + hh * 32 + t];
        out[i * FH + t] = 0.25f * v;
    }
}

extern "C" void kernel_launch(void* const* d_in, const int* in_sizes, int n_in,
                              void* d_out, int out_size, void* d_ws, size_t ws_size,
                              hipStream_t stream) {
    const float* h    = (const float*)d_in[0];
    const int*   adj  = (const int*)d_in[1];
    const float* W    = (const float*)d_in[2];
    const float* attw = (const float*)d_in[3];
    float* out = (float*)d_out;

    float* g = (float*)d_ws;                 // 1024*128 floats = 512 KB
    float* s = g + N_NODES * F_TOT;          // 1024*4 floats = 16 KB

    gat_gemm<<<N_NODES, 128, 0, stream>>>(h, W, attw, g, s);
    gat_attn<<<N_NODES, 256, 0, stream>>>(g, s, adj, attw, out);
}

// Round 2
// 104.701 us; speedup vs baseline: 1.1763x; 1.1763x over previous
//
#include <hip/hip_runtime.h>
#include <math.h>

#define N_NODES 1024
#define NH 4
#define FH 32
#define F_TOT 128

// ---------------- K1: g = h @ W  (K-split, 4 fma chains), s[i][hd] = 0.6-foldable dot ----------------
__global__ __launch_bounds__(256) void gat_gemm(
    const float* __restrict__ h, const float* __restrict__ W,
    const float* __restrict__ attw, float* __restrict__ g, float* __restrict__ s)
{
    const int i = blockIdx.x;
    const int t = threadIdx.x;
    const int c = t & 127, kh = t >> 7;   // col, K-half
    __shared__ float hrow[256];
    __shared__ float part[2][128];

    hrow[t] = h[i * 256 + t];
    __syncthreads();

    const float* __restrict__ Wp = W + (kh * 128) * F_TOT + c;
    const float* __restrict__ hp = hrow + kh * 128;
    float a0 = 0.f, a1 = 0.f, a2 = 0.f, a3 = 0.f;
    #pragma unroll
    for (int k = 0; k < 128; k += 8) {
        a0 = fmaf(hp[k + 0], Wp[(k + 0) * F_TOT], a0);
        a1 = fmaf(hp[k + 1], Wp[(k + 1) * F_TOT], a1);
        a2 = fmaf(hp[k + 2], Wp[(k + 2) * F_TOT], a2);
        a3 = fmaf(hp[k + 3], Wp[(k + 3) * F_TOT], a3);
        a0 = fmaf(hp[k + 4], Wp[(k + 4) * F_TOT], a0);
        a1 = fmaf(hp[k + 5], Wp[(k + 5) * F_TOT], a1);
        a2 = fmaf(hp[k + 6], Wp[(k + 6) * F_TOT], a2);
        a3 = fmaf(hp[k + 7], Wp[(k + 7) * F_TOT], a3);
    }
    part[kh][c] = (a0 + a1) + (a2 + a3);
    __syncthreads();

    if (t < 128) {
        const float gv = part[0][t] + part[1][t];
        g[i * F_TOT + t] = gv;
        float pr = gv * attw[t & 31];
        #pragma unroll
        for (int d = 1; d < 32; d <<= 1) pr += __shfl_xor(pr, d);
        if ((t & 31) == 0) s[i * NH + (t >> 5)] = pr;
    }
}

// ---------------- K2: flash-style fused scores+softmax+aggregation, no LDS staging ----------------
// thread map: wave = head (4 waves); lane = fh*32 + jl; thread owns 16 features,
// all 1024 j (j = step*32 + jl), for 2 nodes (i0, i0+1).
__global__ __launch_bounds__(256, 3) void gat_attn(
    const float* __restrict__ g, const float* __restrict__ s,
    const int* __restrict__ adj, const float* __restrict__ attw,
    float* __restrict__ out)
{
    __shared__ float red[NH][2][2][16];   // [hd][it][fh][k]

    const int t = threadIdx.x;
    const int hd = t >> 6;
    const int lane = t & 63;
    const int fh = lane >> 5;
    const int jl = lane & 31;
    const int i0 = blockIdx.x * 2;

    const float* __restrict__ gbase = g + hd * FH + fh * 16;

    float w04[16], gi[2][16], acc[2][16];
    float m[2], l[2], sib[2];

    #pragma unroll
    for (int u = 0; u < 4; ++u) {
        const float4 wv = *reinterpret_cast<const float4*>(attw + fh * 16 + u * 4);
        w04[u * 4 + 0] = 0.4f * wv.x;
        w04[u * 4 + 1] = 0.4f * wv.y;
        w04[u * 4 + 2] = 0.4f * wv.z;
        w04[u * 4 + 3] = 0.4f * wv.w;
        #pragma unroll
        for (int it = 0; it < 2; ++it) {
            const float4 gv = *reinterpret_cast<const float4*>(gbase + (i0 + it) * F_TOT + u * 4);
            gi[it][u * 4 + 0] = gv.x;
            gi[it][u * 4 + 1] = gv.y;
            gi[it][u * 4 + 2] = gv.z;
            gi[it][u * 4 + 3] = gv.w;
        }
    }
    #pragma unroll
    for (int it = 0; it < 2; ++it) {
        sib[it] = 0.6f * s[(i0 + it) * NH + hd];
        m[it] = -1e38f;
        l[it] = 0.f;
        #pragma unroll
        for (int k = 0; k < 16; ++k) acc[it][k] = 0.f;
    }

    const int* __restrict__ adjr0 = adj + (size_t)i0 * N_NODES;
    const int* __restrict__ adjr1 = adjr0 + N_NODES;

    #pragma unroll 2
    for (int step = 0; step < 32; ++step) {
        const int j = step * 32 + jl;
        float gjv[16];
        #pragma unroll
        for (int u = 0; u < 4; ++u) {
            const float4 v = *reinterpret_cast<const float4*>(gbase + j * F_TOT + u * 4);
            gjv[u * 4 + 0] = v.x;
            gjv[u * 4 + 1] = v.y;
            gjv[u * 4 + 2] = v.z;
            gjv[u * 4 + 3] = v.w;
        }
        const float sj = s[j * NH + hd];
        const int am0 = adjr0[j];
        const int am1 = adjr1[j];

        #pragma unroll
        for (int it = 0; it < 2; ++it) {
            float e0 = 0.f, e1 = 0.f, e2 = 0.f, e3 = 0.f;
            #pragma unroll
            for (int k = 0; k < 16; k += 4) {
                e0 = fmaf(w04[k + 0], fabsf(gi[it][k + 0] + gjv[k + 0]), e0);
                e1 = fmaf(w04[k + 1], fabsf(gi[it][k + 1] + gjv[k + 1]), e1);
                e2 = fmaf(w04[k + 2], fabsf(gi[it][k + 2] + gjv[k + 2]), e2);
                e3 = fmaf(w04[k + 3], fabsf(gi[it][k + 3] + gjv[k + 3]), e3);
            }
            float eh = (e0 + e1) + (e2 + e3);
            eh += __shfl_xor(eh, 32);                 // combine the two feature-halves
            float e = fmaf(0.6f, sj, sib[it]) + eh;
            const int am = (it == 0) ? am0 : am1;
            e = am ? e : -3e38f;                      // mask non-edges (finite sentinel, no NaN)

            if (e > m[it]) {                          // rare (~H_1024 times per row)
                const float sc = __expf(m[it] - e);
                l[it] *= sc;
                #pragma unroll
                for (int k = 0; k < 16; ++k) acc[it][k] *= sc;
                m[it] = e;
            }
            const float p = __expf(e - m[it]);
            l[it] += p;
            #pragma unroll
            for (int k = 0; k < 16; ++k) acc[it][k] = fmaf(p, gjv[k], acc[it][k]);
        }
    }

    // merge (m,l,acc) across the 32 jl-lanes of each fh-group, then head-mean via tiny LDS
    #pragma unroll
    for (int it = 0; it < 2; ++it) {
        float mm = m[it];
        #pragma unroll
        for (int d = 1; d < 32; d <<= 1) mm = fmaxf(mm, __shfl_xor(mm, d));
        const float sc = __expf(m[it] - mm);
        float ll = l[it] * sc;
        #pragma unroll
        for (int k = 0; k < 16; ++k) acc[it][k] *= sc;
        #pragma unroll
        for (int d = 1; d < 32; d <<= 1) {
            ll += __shfl_xor(ll, d);
            #pragma unroll
            for (int k = 0; k < 16; ++k) acc[it][k] += __shfl_xor(acc[it][k], d);
        }
        const float inv = 0.25f / ll;                 // fold head-mean and softmax denom
        if (jl == 0) {
            #pragma unroll
            for (int k = 0; k < 16; ++k) red[hd][it][fh][k] = acc[it][k] * inv;
        }
    }
    __syncthreads();

    if (t < 64) {
        const int it = t >> 5, f = t & 31;
        const int fi = f >> 4, k = f & 15;
        const float v = red[0][it][fi][k] + red[1][it][fi][k]
                      + red[2][it][fi][k] + red[3][it][fi][k];
        out[(i0 + it) * FH + f] = v;
    }
}

extern "C" void kernel_launch(void* const* d_in, const int* in_sizes, int n_in,
                              void* d_out, int out_size, void* d_ws, size_t ws_size,
                              hipStream_t stream) {
    const float* h    = (const float*)d_in[0];
    const int*   adj  = (const int*)d_in[1];
    const float* W    = (const float*)d_in[2];
    const float* attw = (const float*)d_in[3];
    float* out = (float*)d_out;

    float* g = (float*)d_ws;                 // 1024*128 floats = 512 KB
    float* s = g + N_NODES * F_TOT;          // 1024*4  floats = 16 KB

    gat_gemm<<<N_NODES, 256, 0, stream>>>(h, W, attw, g, s);
    gat_attn<<<N_NODES / 2, 256, 0, stream>>>(g, s, adj, attw, out);
}